// Round 1
// baseline (9290.667 us; speedup 1.0000x reference)
//
#include <hip/hip_runtime.h>

#define HID   1024
#define TLEN  512
#define VOC   128
#define NBLK  256         // = #CUs; 1 block/CU (132KB LDS) -> all co-resident
#define NW    32          // worker team: all 32 blocks of the winner XCD
#define LDSK  1032        // padded LDS row stride
#define HBUF  (64 * HID)  // one h buffer (elements)

typedef __bf16 bf16_t;
typedef __attribute__((ext_vector_type(8))) __bf16 bf16x8;
typedef __attribute__((ext_vector_type(4))) float  f32x4;

__device__ __forceinline__ float sigmoid_fast(float x) {
  return 1.0f / (1.0f + __expf(-x));
}
__device__ __forceinline__ float tanh_fast(float x) {
  float e = __expf(-2.0f * x);
  return (1.0f - e) / (1.0f + e);
}

union PairU { bf16_t b[2]; unsigned u; };

// L1-only invalidate: local to this CU. Data/flags live in the winner XCD's
// shared L2 (vector L1 is write-through), so L1-inv + plain load is a fresh
// same-XCD read with ~L2 latency — no MALL round trip.
__device__ __forceinline__ void l1_inv() {
  asm volatile("buffer_inv" ::: "memory");
}

__device__ __forceinline__ bf16x8 ldw(const bf16_t* p) {
  return *reinterpret_cast<const bf16x8*>(p);
}

// Team-local flag wait: 32 per-producer epoch words on one 128B line in the
// winner XCD's L2. Wave 0 polls with a single coalesced 32-lane load per
// iteration (lanes 32-63 duplicate). This replaces the previous agent-scope
// (MALL) counter protocol — the source of the invariant ~8.25us/hop.
__device__ __forceinline__ void wait_flags(const unsigned* f, unsigned tgt) {
  if (threadIdx.x < 64) {
    const volatile unsigned* p =
        (const volatile unsigned*)(f + (threadIdx.x & 31));
    for (;;) {
      l1_inv();
      unsigned v = *p;
      if (__all((int)(v - tgt) >= 0)) break;   // wrap-safe compare
      __builtin_amdgcn_s_sleep(1);
    }
  }
  __syncthreads();
}

// publish: __syncthreads drains this block's write-through data stores into
// L2 (vmcnt(0) before s_barrier), then one plain store of the epoch value.
// Same-XCD consumers see the line update in place.
__device__ __forceinline__ void publish(unsigned* fw, unsigned v) {
  __syncthreads();
  if (threadIdx.x == 0) *(volatile unsigned*)fw = v;
}

#define MFMA(a, b, c) __builtin_amdgcn_mfma_f32_16x16x32_bf16((a), (b), (c), 0, 0, 0)

__global__ void __launch_bounds__(256, 1)
gru_team(const int* __restrict__ X,
         const float* __restrict__ Wr_x, const float* __restrict__ Wr_h, const float* __restrict__ b_r,
         const float* __restrict__ Wz_x, const float* __restrict__ Wz_h, const float* __restrict__ b_z,
         const float* __restrict__ Wh_x, const float* __restrict__ Wh_h, const float* __restrict__ b_h,
         const float* __restrict__ W_o,  const float* __restrict__ b_o,
         float* __restrict__ out,
         bf16_t* __restrict__ hring, bf16_t* __restrict__ rh_bf,
         bf16_t* __restrict__ wz_bf, bf16_t* __restrict__ wo_bf,
         unsigned* __restrict__ flags)
{
  __shared__ __align__(16) bf16_t Wbuf[2 * 32 * LDSK];  // Wr + Wh slices, 132KB
  __shared__ int s_role;

  unsigned* fH     = flags;        // words [0,32): h-epoch per producer block
  unsigned* fR     = flags + 32;   // words [32,64): rh-epoch per producer
  unsigned* cnt    = flags + 128;  // per-XCD claim counters (MALL atomics only)
  unsigned* winner = flags + 160;  // 0 = unset, else xcd+1
  unsigned* ready  = flags + 168;  // one-time team barrier (MALL atomics only)

  const int tid  = threadIdx.x;
  const int lane = tid & 63;
  const int wv   = tid >> 6;
  const int n16  = lane & 15;
  const int q    = lane >> 4;
  const int aoff = (wv * 16 + n16) * HID + q * 8;

  int bi[4];
#pragma unroll
  for (int i = 0; i < 4; ++i) bi[i] = wv * 16 + q * 4 + i;

  // ---------- self-organize: first XCD to seat 32 blocks = worker team ------
  if (tid == 0) {
    unsigned xcc;
    asm volatile("s_getreg_b32 %0, hwreg(HW_REG_XCC_ID)" : "=s"(xcc));
    xcc &= 7u;
    unsigned idx = __hip_atomic_fetch_add(&cnt[xcc], 1u, __ATOMIC_RELAXED, __HIP_MEMORY_SCOPE_AGENT);
    if (idx == NW - 1) {
      unsigned exp = 0u;
      __hip_atomic_compare_exchange_strong(winner, &exp, xcc + 1u,
          __ATOMIC_RELAXED, __ATOMIC_RELAXED, __HIP_MEMORY_SCOPE_AGENT);
    }
    unsigned w;
    do {
      w = __hip_atomic_load(winner, __ATOMIC_RELAXED, __HIP_MEMORY_SCOPE_AGENT);
      __builtin_amdgcn_s_sleep(1);
    } while (w == 0u);   // guaranteed: 256 blocks over 8 XCDs -> some XCD hits 32
    s_role = (xcc == w - 1u && idx < NW) ? (int)idx : -1;
  }
  __syncthreads();
  const int role = s_role;
  if (role < 0) return;   // losers exit; out-heads no longer exist

  const int s  = role;
  const int c0 = s * 32;

  // Reset my epoch words IN THIS XCD'S L2. A plain store updates a possibly
  // stale (previous-replay) line in place; the ready-barrier below makes all
  // 32 zero-stores visible before any block's first poll. Replay/garbage-safe.
  if (tid == 0) {
    *(volatile unsigned*)&fH[s] = 0u;
    *(volatile unsigned*)&fR[s] = 0u;
  }

  // ---------- staging: Wr/Wh -> LDS, Wz slice -> L2, W_o slice -> L2 --------
  for (int idx = tid; idx < 32 * HID; idx += 256) {
    int n = idx & 31, k = idx >> 5;
    int r = (n & 1) * 16 + (n >> 1);
    Wbuf[r * LDSK + k]             = (bf16_t)Wr_h[k * HID + c0 + n];
    Wbuf[32 * LDSK + r * LDSK + k] = (bf16_t)Wh_h[k * HID + c0 + n];
  }
  bf16_t* wzs = wz_bf + s * (32 * 1024);
  for (int idx = tid; idx < 32 * HID; idx += 256) {
    int n = idx & 31, k = idx >> 5;
    int r = (n & 1) * 16 + (n >> 1);
    wzs[r * 1024 + k] = (bf16_t)Wz_h[k * HID + c0 + n];
  }
  if (s < 8) {
    // shared W_o slices: block s stages vocab cols [16s, 16s+16)
    bf16_t* wos = wo_bf + s * (16 * 1024);
    for (int idx = tid; idx < 16 * HID; idx += 256) {
      int n = idx & 15, k = idx >> 4;
      wos[n * 1024 + k] = (bf16_t)W_o[k * VOC + s * 16 + n];
    }
  }
  const int j0 = c0 + 2 * n16;
#pragma unroll
  for (int i = 0; i < 4; ++i) {
    PairU zz; zz.b[0] = (bf16_t)0.f; zz.b[1] = (bf16_t)0.f;
    *reinterpret_cast<PairU*>(hring + bi[i] * HID + j0) = zz;   // h_0 = 0
  }
  __syncthreads();   // drains flag-zeroes + staging + h0 (vmcnt(0) at barrier)

  // one-time team-wide MALL barrier: orders all zero-stores/staging before
  // any block's first L2 flag poll.
  if (tid == 0) {
    __hip_atomic_fetch_add(ready, 1u, __ATOMIC_RELAXED, __HIP_MEMORY_SCOPE_AGENT);
    while (__hip_atomic_load(ready, __ATOMIC_RELAXED, __HIP_MEMORY_SCOPE_AGENT) < NW)
      __builtin_amdgcn_s_sleep(1);
  }
  __syncthreads();
  if (tid == 0) *(volatile unsigned*)&fH[s] = 1u;   // h slot 0 ready

  // ---------- per-step constants ----------
  const float br0 = b_r[j0], br1 = b_r[j0 + 1];
  const float bz0 = b_z[j0], bz1 = b_z[j0 + 1];
  const float bh0 = b_h[j0], bh1 = b_h[j0 + 1];
  const bf16_t* wr0 = &Wbuf[n16 * LDSK + q * 8];
  const bf16_t* wr1 = &Wbuf[(16 + n16) * LDSK + q * 8];
  const bf16_t* wh0 = &Wbuf[32 * LDSK + n16 * LDSK + q * 8];
  const bf16_t* wh1 = &Wbuf[32 * LDSK + (16 + n16) * LDSK + q * 8];
  const bf16_t* wz0 = wzs + n16 * 1024 + q * 8;
  const bf16_t* wz1 = wzs + (16 + n16) * 1024 + q * 8;
  const bf16_t* rhrow = rh_bf + aoff;

  // out-projection ownership: block s owns out tile (row-tile rt, vocab-tile
  // vt), computed by wave rt (whose areg holds exactly rows rt*16..rt*16+15).
  const int rt = s >> 3, vt = s & 7;
  const bool outw = (wv == rt);
  const bf16_t* wop = wo_bf + vt * (16 * 1024) + n16 * 1024 + q * 8;
  const float bo = b_o[vt * 16 + n16];

  f32x4 hm0 = {0.f,0.f,0.f,0.f}, hm1 = {0.f,0.f,0.f,0.f};  // fp32 h master

  for (int t = 0; t < TLEN; ++t) {
    // prefetch x-gathers (hidden under the hop-A poll)
    float gr0[4], gr1[4], gz0[4], gz1[4], gh0[4], gh1[4];
#pragma unroll
    for (int i = 0; i < 4; ++i) {
      int xb = X[bi[i] * TLEN + t];
      gr0[i] = Wr_x[xb * HID + j0]; gr1[i] = Wr_x[xb * HID + j0 + 1];
      gz0[i] = Wz_x[xb * HID + j0]; gz1[i] = Wz_x[xb * HID + j0 + 1];
      gh0[i] = Wh_x[xb * HID + j0]; gh1[i] = Wh_x[xb * HID + j0 + 1];
    }

    // ---- hop A: h_t ready ----
    wait_flags(fH, (unsigned)(t + 1));
    l1_inv();
    const bf16_t* hrow = hring + (t & 1) * HBUF + aoff;
    bf16x8 areg[32];
#pragma unroll
    for (int kk = 0; kk < 32; ++kk) areg[kk] = ldw(hrow + kk * 32);

    // ---- r phase (critical; 4 independent MFMA chains) ----
    f32x4 aR0 = {0.f,0.f,0.f,0.f}, aR1 = {0.f,0.f,0.f,0.f};
    f32x4 bR0 = {0.f,0.f,0.f,0.f}, bR1 = {0.f,0.f,0.f,0.f};
#pragma unroll
    for (int kk = 0; kk < 16; ++kk) {
      aR0 = MFMA(areg[kk],      ldw(wr0 + kk * 32),        aR0);
      aR1 = MFMA(areg[kk],      ldw(wr1 + kk * 32),        aR1);
      bR0 = MFMA(areg[kk + 16], ldw(wr0 + (kk + 16) * 32), bR0);
      bR1 = MFMA(areg[kk + 16], ldw(wr1 + (kk + 16) * 32), bR1);
    }
    aR0 += bR0; aR1 += bR1;
#pragma unroll
    for (int i = 0; i < 4; ++i) {
      float r0 = sigmoid_fast(aR0[i] + br0 + gr0[i]);
      float r1 = sigmoid_fast(aR1[i] + br1 + gr1[i]);
      PairU c;
      c.b[0] = (bf16_t)(r0 * hm0[i]);   // fp32 register master (== h_t here)
      c.b[1] = (bf16_t)(r1 * hm1[i]);
      *reinterpret_cast<PairU*>(rh_bf + bi[i] * HID + j0) = c;  // local L2
    }
    publish(&fR[s], (unsigned)(t + 1));

    // ---- out[t-1] = h_t @ W_o (shadowed: after rh publish, before hop B) ----
    if (outw && t) {
      f32x4 oa = {0.f,0.f,0.f,0.f}, ob = {0.f,0.f,0.f,0.f};
#pragma unroll
      for (int kk = 0; kk < 16; ++kk) {
        oa = MFMA(areg[kk],      ldw(wop + kk * 32),        oa);
        ob = MFMA(areg[kk + 16], ldw(wop + (kk + 16) * 32), ob);
      }
      oa += ob;
#pragma unroll
      for (int i = 0; i < 4; ++i)
        out[(bi[i] * TLEN + (t - 1)) * VOC + vt * 16 + n16] = oa[i] + bo;
    }

    // ---- z phase (shadow; reuses areg, streams wz from local L2) ----
    f32x4 aZ0 = {0.f,0.f,0.f,0.f}, aZ1 = {0.f,0.f,0.f,0.f};
    f32x4 bZ0 = {0.f,0.f,0.f,0.f}, bZ1 = {0.f,0.f,0.f,0.f};
#pragma unroll
    for (int kk = 0; kk < 16; ++kk) {
      aZ0 = MFMA(areg[kk],      ldw(wz0 + kk * 32),        aZ0);
      aZ1 = MFMA(areg[kk],      ldw(wz1 + kk * 32),        aZ1);
      bZ0 = MFMA(areg[kk + 16], ldw(wz0 + (kk + 16) * 32), bZ0);
      bZ1 = MFMA(areg[kk + 16], ldw(wz1 + (kk + 16) * 32), bZ1);
    }
    aZ0 += bZ0; aZ1 += bZ1;
    f32x4 z0, z1;
#pragma unroll
    for (int i = 0; i < 4; ++i) {
      z0[i] = sigmoid_fast(aZ0[i] + bz0 + gz0[i]);
      z1[i] = sigmoid_fast(aZ1[i] + bz1 + gz1[i]);
    }

    // ---- hop B: rh ready; h_tilde phase (critical) ----
    wait_flags(fR, (unsigned)(t + 1));
    l1_inv();
    bf16x8 breg[32];
#pragma unroll
    for (int kk = 0; kk < 32; ++kk) breg[kk] = ldw(rhrow + kk * 32);
    f32x4 aH0 = {0.f,0.f,0.f,0.f}, aH1 = {0.f,0.f,0.f,0.f};
    f32x4 bH0 = {0.f,0.f,0.f,0.f}, bH1 = {0.f,0.f,0.f,0.f};
#pragma unroll
    for (int kk = 0; kk < 16; ++kk) {
      aH0 = MFMA(breg[kk],      ldw(wh0 + kk * 32),        aH0);
      aH1 = MFMA(breg[kk],      ldw(wh1 + kk * 32),        aH1);
      bH0 = MFMA(breg[kk + 16], ldw(wh0 + (kk + 16) * 32), bH0);
      bH1 = MFMA(breg[kk + 16], ldw(wh1 + (kk + 16) * 32), bH1);
    }
    aH0 += bH0; aH1 += bH1;
    bf16_t* hnext = hring + ((t + 1) & 1) * HBUF;
#pragma unroll
    for (int i = 0; i < 4; ++i) {
      float ht0 = tanh_fast(aH0[i] + bh0 + gh0[i]);
      float ht1 = tanh_fast(aH1[i] + bh1 + gh1[i]);
      float hn0 = z0[i] * hm0[i] + (1.f - z0[i]) * ht0;
      float hn1 = z1[i] * hm1[i] + (1.f - z1[i]) * ht1;
      hm0[i] = hn0; hm1[i] = hn1;
      PairU c; c.b[0] = (bf16_t)hn0; c.b[1] = (bf16_t)hn1;
      *reinterpret_cast<PairU*>(hnext + bi[i] * HID + j0) = c;  // local L2
    }
    publish(&fH[s], (unsigned)(t + 2));
  }

  // ---- epilogue: out[TLEN-1] = h_TLEN @ W_o ----
  wait_flags(fH, (unsigned)(TLEN + 1));
  l1_inv();
  if (outw) {
    const bf16_t* hrow = hring + (TLEN & 1) * HBUF + aoff;
    bf16x8 areg[32];
#pragma unroll
    for (int kk = 0; kk < 32; ++kk) areg[kk] = ldw(hrow + kk * 32);
    f32x4 oa = {0.f,0.f,0.f,0.f}, ob = {0.f,0.f,0.f,0.f};
#pragma unroll
    for (int kk = 0; kk < 16; ++kk) {
      oa = MFMA(areg[kk],      ldw(wop + kk * 32),        oa);
      ob = MFMA(areg[kk + 16], ldw(wop + (kk + 16) * 32), ob);
    }
    oa += ob;
#pragma unroll
    for (int i = 0; i < 4; ++i)
      out[(bi[i] * TLEN + (TLEN - 1)) * VOC + vt * 16 + n16] = oa[i] + bo;
  }

  // write back dirty L2 so the next replay (possibly a different winner XCD)
  // never races two dirty copies at the MALL.
  __builtin_amdgcn_fence(__ATOMIC_RELEASE, "agent");
}

extern "C" void kernel_launch(void* const* d_in, const int* in_sizes, int n_in,
                              void* d_out, int out_size, void* d_ws, size_t ws_size,
                              hipStream_t stream) {
  const int*   X    = (const int*)d_in[0];
  const float* Wr_x = (const float*)d_in[1];
  const float* Wr_h = (const float*)d_in[2];
  const float* b_r  = (const float*)d_in[3];
  const float* Wz_x = (const float*)d_in[4];
  const float* Wz_h = (const float*)d_in[5];
  const float* b_z  = (const float*)d_in[6];
  const float* Wh_x = (const float*)d_in[7];
  const float* Wh_h = (const float*)d_in[8];
  const float* b_h  = (const float*)d_in[9];
  const float* W_o  = (const float*)d_in[10];
  const float* b_o  = (const float*)d_in[11];

  char* ws = (char*)d_ws;
  // layout: [flags 4KB | hring 2x128KB | rh 128KB | wz 2MB | wo 256KB]
  unsigned* flags = (unsigned*)ws;
  bf16_t*   hring = (bf16_t*)(ws + 4096);
  bf16_t*   rh_bf = (bf16_t*)(ws + 4096 + 2 * HBUF * sizeof(bf16_t));
  bf16_t*   wz_bf = (bf16_t*)(ws + 4096 + 3 * HBUF * sizeof(bf16_t));
  bf16_t*   wo_bf = (bf16_t*)(ws + 4096 + 3 * HBUF * sizeof(bf16_t)
                              + (size_t)NW * 32 * HID * sizeof(bf16_t));

  // zero election/claim state (MALL-atomic-accessed words only need this;
  // the fH/fR epoch words are additionally re-zeroed in-L2 by the workers)
  hipMemsetAsync(ws, 0, 4096, stream);

  gru_team<<<NBLK, 256, 0, stream>>>(
      X, Wr_x, Wr_h, b_r, Wz_x, Wz_h, b_z, Wh_x, Wh_h, b_h, W_o, b_o,
      (float*)d_out, hring, rh_bf, wz_bf, wo_bf, flags);
}